// Round 14
// baseline (291.315 us; speedup 1.0000x reference)
//
#include <hip/hip_runtime.h>
#include <cstdint>
#include <cstddef>

// ---------------------------------------------------------------------------
// GCN encoder: z = GCN3( relu(GCN2( relu(GCN1( LN(x) )) )) )
// R25: phase-A restructure only, vs R21 baseline (259.5us, agg128=45.5us).
//      R23 (occupancy) and R24 (dinv traffic) both falsified; revised model:
//      gather is LATENCY-SERIAL (VGPR<=64 forbids loop double-buffering) with
//      per-group LOAD IMBALANCE (row-per-16-lane-group). New phase A = R7
//      wave-per-node: 64 lanes/node, 4 quarter-waves stride-4 over edges
//      (16 edges per latency step vs 4), shfl_xor(16/32) reduce; each wave
//      does 8 nodes sequentially. Phase B + everything else identical to R21.
//      CONSTRAINT: agg_gemm <= 64 VGPR (R19/R20 cliff).
// ---------------------------------------------------------------------------

typedef __attribute__((ext_vector_type(8))) __bf16 bf16x8;
typedef __attribute__((ext_vector_type(4))) float f32x4;
typedef _Float16 half_t;
typedef __attribute__((ext_vector_type(8))) _Float16 half8_t;

#define NHIST 256
#define CHUNK 4096
#define MAXB 8192

// ---------------- prep: hist x256 | wsplit x3, by block range --------------
__global__ __launch_bounds__(256) void prep_misc(
    const int* __restrict__ dst,
    const float* __restrict__ W1, const float* __restrict__ W2,
    const float* __restrict__ W3,
    int* __restrict__ bcnt_multi,
    unsigned short* __restrict__ W1t_hi, unsigned short* __restrict__ W1t_lo,
    unsigned short* __restrict__ W2t_hi, unsigned short* __restrict__ W2t_lo,
    unsigned short* __restrict__ W3t_hi, unsigned short* __restrict__ W3t_lo,
    int E) {
  int blk = blockIdx.x;
  int tid = threadIdx.x;
  if (blk < NHIST) {
    __shared__ int h[256];
    h[tid] = 0;
    __syncthreads();
    for (int e = blk * 256 + tid; e < E; e += NHIST * 256)
      atomicAdd(&h[dst[e] >> 8], 1);
    __syncthreads();
    bcnt_multi[blk * 256 + tid] = h[tid];
    return;
  }
  int idx = (blk - NHIST) * 256 + tid;
  if (idx < 32768) {
    // W1: bf16 hi/lo (layer-1 bf16-triple path)
    int k = idx / 128, c = idx % 128;
    float v = W1[idx];
    __bf16 h = (__bf16)v;
    __bf16 l = (__bf16)(v - (float)h);
    W1t_hi[(size_t)c * 256 + k] = __builtin_bit_cast(unsigned short, h);
    W1t_lo[(size_t)c * 256 + k] = __builtin_bit_cast(unsigned short, l);
    return;
  }
  // W2/W3: fp16 hi + fp16 lo*2048 (f16 dual-MFMA path)
  const float* W;
  unsigned short *Th, *Tl;
  int K, NOUT;
  if (idx < 49152) {
    idx -= 32768;
    W = W2; Th = W2t_hi; Tl = W2t_lo; K = 128; NOUT = 128;
  } else {
    idx -= 49152;
    W = W3; Th = W3t_hi; Tl = W3t_lo; K = 128; NOUT = 64;
  }
  int k = idx / NOUT, c = idx % NOUT;
  float v = W[idx];
  half_t h = (half_t)v;
  half_t l = (half_t)((v - (float)h) * 2048.0f);
  Th[(size_t)c * K + k] = __builtin_bit_cast(unsigned short, h);
  Tl[(size_t)c * K + k] = __builtin_bit_cast(unsigned short, l);
}

// ---------------- scan: sum 256 slices, exclusive prefix ----------------
__global__ __launch_bounds__(256) void scan_buckets(const int* __restrict__ bcnt_multi,
                                                    int* __restrict__ bbase,
                                                    int* __restrict__ bcur, int NB, int E) {
  __shared__ int tmp[256];
  int t = threadIdx.x;
  int v = 0;
  for (int h = 0; h < NHIST; ++h) v += bcnt_multi[h * 256 + t];
  tmp[t] = v;
  __syncthreads();
  for (int off = 1; off < 256; off <<= 1) {
    int x = (t >= off) ? tmp[t - off] : 0;
    __syncthreads();
    tmp[t] += x;
    __syncthreads();
  }
  int excl = tmp[t] - v;
  if (t < NB) { bbase[t] = excl; bcur[t] = excl; }
  if (t == 0) bbase[NB] = E;
}

// ---------------- scatter body (smem: 20480 B) ----------------
// record = (dst << 16) | src  (both < 65536)
__device__ __forceinline__ void scatter_body(char* smem_raw, int bid,
                                             const int* __restrict__ src,
                                             const int* __restrict__ dst,
                                             int* __restrict__ bcur,
                                             unsigned int* __restrict__ binned, int E) {
  unsigned int* recs = (unsigned int*)smem_raw;          // 16384 B
  int* hist = (int*)(smem_raw + 16384);
  int* lbase = hist + 256;
  int* resv = lbase + 256;
  int* cur = resv + 256;
  int t = threadIdx.x;
  int e0 = bid * CHUNK;
  if (e0 >= E) return;
  int len = min(CHUNK, E - e0);
  hist[t] = 0;
  cur[t] = 0;
  __syncthreads();
  for (int i = t; i < len; i += 256) atomicAdd(&hist[dst[e0 + i] >> 8], 1);
  __syncthreads();
  int v = hist[t];
  lbase[t] = v;
  __syncthreads();
  for (int off = 1; off < 256; off <<= 1) {
    int x = (t >= off) ? lbase[t - off] : 0;
    __syncthreads();
    lbase[t] += x;
    __syncthreads();
  }
  int myexcl = lbase[t] - v;
  if (v) resv[t] = atomicAdd(&bcur[t], v);
  __syncthreads();
  lbase[t] = myexcl;
  __syncthreads();
  for (int i = t; i < len; i += 256) {
    int d = dst[e0 + i], s = src[e0 + i];
    int b = d >> 8;
    int r = atomicAdd(&cur[b], 1);
    recs[lbase[b] + r] = ((unsigned int)d << 16) | (unsigned int)s;
  }
  __syncthreads();
  for (int i = t; i < len; i += 256) {
    unsigned int rc = recs[i];
    int b = rc >> 24;
    binned[resv[b] + (i - lbase[b])] = rc;
  }
}

// ---------------- sort body (smem: 36864 B) ----------------
__device__ __forceinline__ void sort_body(char* smem_raw, int b,
                                          const unsigned int* __restrict__ binned,
                                          const int* __restrict__ bbase,
                                          int* __restrict__ srcs,
                                          int* __restrict__ offs,
                                          float* __restrict__ dinv,
                                          int N, int NB, int E) {
  int* sstage = (int*)smem_raw;                           // 32768 B
  int* hist = (int*)(smem_raw + 32768);
  int* nbase = hist + 256;
  int* cur = nbase + 256;
  int* tmp = cur + 256;
  int t = threadIdx.x;
  int base = bbase[b], end = bbase[b + 1];
  int L = end - base;
  if (L > MAXB) L = MAXB;
  hist[t] = 0;
  __syncthreads();
  for (int i = t; i < L; i += 256)
    atomicAdd(&hist[(binned[base + i] >> 16) & 255], 1);
  __syncthreads();
  int v = hist[t];
  tmp[t] = v;
  __syncthreads();
  for (int off = 1; off < 256; off <<= 1) {
    int x = (t >= off) ? tmp[t - off] : 0;
    __syncthreads();
    tmp[t] += x;
    __syncthreads();
  }
  int excl = tmp[t] - v;
  nbase[t] = excl;
  cur[t] = excl;
  int node = (b << 8) + t;
  if (node < N) {
    offs[node] = base + excl;
    dinv[node] = rsqrtf(1.0f + (float)v);
  }
  if (b == NB - 1 && t == 0) offs[N] = E;
  __syncthreads();
  for (int i = t; i < L; i += 256) {
    unsigned int p = binned[base + i];
    int ld = (p >> 16) & 255;
    int slot = atomicAdd(&cur[ld], 1);
    sstage[slot] = (int)(p & 0xFFFFu);
  }
  __syncthreads();
  for (int i = t; i < L; i += 256) srcs[base + i] = sstage[i];
}

// ---------------- GEMM1 body: BM=32, bf16 hi/lo triple-MFMA, LN fused ------
template <int K, int NOUT, bool LN>
__device__ __forceinline__ void gemm_body(char* smem_raw, int gbid,
                                          const float* __restrict__ A,
                                          const unsigned short* __restrict__ Wt_hi,
                                          const unsigned short* __restrict__ Wt_lo,
                                          const float* __restrict__ gamma,
                                          const float* __restrict__ beta,
                                          half_t* __restrict__ out, int nrows) {
  constexpr int BM = 32, BK = 32, BKP = BK + 8;
  constexpr int NTW = NOUT / 32;

  const int tid = threadIdx.x;
  const int lane = tid & 63;
  const int w = tid >> 6;
  const int quad = lane >> 4;
  const int l16 = lane & 15;
  const int rg = (w & 1) * 16;
  const int cg = (w >> 1) * (NOUT / 2);
  const int row0 = gbid * BM;

  unsigned short* As_hi = (unsigned short*)smem_raw;
  unsigned short* As_lo = As_hi + BM * BKP;
  unsigned short* Bs_hi = As_lo + BM * BKP;
  unsigned short* Bs_lo = Bs_hi + NOUT * BKP;
  float* mu_s = (float*)(Bs_lo + NOUT * BKP);
  float* rs_s = mu_s + BM;

  if constexpr (LN) {
    int r = tid >> 3;
    int part = tid & 7;
    int grow = row0 + r;
    if (grow > nrows - 1) grow = nrows - 1;
    const float4* rp = (const float4*)(A + (size_t)grow * K);
    float s = 0.f, s2 = 0.f;
#pragma unroll
    for (int j = 0; j < K / 32; ++j) {
      float4 v = rp[part * (K / 32) + j];
      s += v.x + v.y + v.z + v.w;
      s2 += v.x * v.x + v.y * v.y + v.z * v.z + v.w * v.w;
    }
    s += __shfl_xor(s, 1);
    s += __shfl_xor(s, 2);
    s += __shfl_xor(s, 4);
    s2 += __shfl_xor(s2, 1);
    s2 += __shfl_xor(s2, 2);
    s2 += __shfl_xor(s2, 4);
    if (part == 0) {
      float m = s * (1.0f / (float)K);
      float var = s2 * (1.0f / (float)K) - m * m;
      mu_s[r] = m;
      rs_s[r] = rsqrtf(var + 1e-5f);
    }
    __syncthreads();
  }

  f32x4 acc[NTW];
#pragma unroll
  for (int t = 0; t < NTW; ++t) acc[t] = (f32x4){0.f, 0.f, 0.f, 0.f};

  for (int k0 = 0; k0 < K; k0 += BK) {
    {
      int r = tid >> 3;
      int c4 = (tid & 7) * 4;
      int grow = row0 + r;
      if (grow > nrows - 1) grow = nrows - 1;
      float4 v = *(const float4*)&A[(size_t)grow * K + k0 + c4];
      if constexpr (LN) {
        float m = mu_s[r], s = rs_s[r];
        float4 g = *(const float4*)&gamma[k0 + c4];
        float4 b = *(const float4*)&beta[k0 + c4];
        v.x = (v.x - m) * s * g.x + b.x;
        v.y = (v.y - m) * s * g.y + b.y;
        v.z = (v.z - m) * s * g.z + b.z;
        v.w = (v.w - m) * s * g.w + b.w;
      }
      float vv[4] = {v.x, v.y, v.z, v.w};
#pragma unroll
      for (int j = 0; j < 4; ++j) {
        __bf16 h = (__bf16)vv[j];
        __bf16 l = (__bf16)(vv[j] - (float)h);
        As_hi[r * BKP + c4 + j] = __builtin_bit_cast(unsigned short, h);
        As_lo[r * BKP + c4 + j] = __builtin_bit_cast(unsigned short, l);
      }
    }
#pragma unroll
    for (int i = 0; i < NOUT / 64; ++i) {
      int n = i * 64 + (tid >> 2);
      int c8 = (tid & 3) * 8;
      *(uint4*)&Bs_hi[n * BKP + c8] = *(const uint4*)&Wt_hi[(size_t)n * K + k0 + c8];
      *(uint4*)&Bs_lo[n * BKP + c8] = *(const uint4*)&Wt_lo[(size_t)n * K + k0 + c8];
    }
    __syncthreads();

    bf16x8 ah = *(const bf16x8*)&As_hi[(rg + l16) * BKP + quad * 8];
    bf16x8 al = *(const bf16x8*)&As_lo[(rg + l16) * BKP + quad * 8];
#pragma unroll
    for (int t = 0; t < NTW; ++t) {
      bf16x8 bh = *(const bf16x8*)&Bs_hi[(cg + t * 16 + l16) * BKP + quad * 8];
      bf16x8 bl = *(const bf16x8*)&Bs_lo[(cg + t * 16 + l16) * BKP + quad * 8];
      acc[t] = __builtin_amdgcn_mfma_f32_16x16x32_bf16(ah, bh, acc[t], 0, 0, 0);
      acc[t] = __builtin_amdgcn_mfma_f32_16x16x32_bf16(al, bh, acc[t], 0, 0, 0);
      acc[t] = __builtin_amdgcn_mfma_f32_16x16x32_bf16(ah, bl, acc[t], 0, 0, 0);
    }
    __syncthreads();
  }

#pragma unroll
  for (int t = 0; t < NTW; ++t) {
#pragma unroll
    for (int r = 0; r < 4; ++r) {
      int grow = row0 + rg + quad * 4 + r;
      if (grow < nrows)
        out[(size_t)grow * NOUT + cg + t * 16 + l16] = (half_t)acc[t][r];
    }
  }
}

constexpr int GEMM1_SMEM = 32 * 40 * 4 + 128 * 40 * 4 + 256;  // 25856

__global__ __launch_bounds__(256) void fused_scatter_gemm1(
    const int* __restrict__ src, const int* __restrict__ dst,
    int* __restrict__ bcur, unsigned int* __restrict__ binned, int E,
    const float* __restrict__ x,
    const unsigned short* __restrict__ W1t_hi, const unsigned short* __restrict__ W1t_lo,
    const float* __restrict__ gamma, const float* __restrict__ beta,
    half_t* __restrict__ t, int nrows, int nscat) {
  __shared__ __align__(16) char smem[GEMM1_SMEM];
  if ((int)blockIdx.x < nscat)
    scatter_body(smem, blockIdx.x, src, dst, bcur, binned, E);
  else
    gemm_body<256, 128, true>(smem, blockIdx.x - nscat, x, W1t_hi, W1t_lo,
                              gamma, beta, t, nrows);
}

__global__ __launch_bounds__(256) void fused_sort_gemm1(
    const unsigned int* __restrict__ binned, const int* __restrict__ bbase,
    int* __restrict__ srcs, int* __restrict__ offs, float* __restrict__ dinv,
    int N, int NB, int E,
    const float* __restrict__ x,
    const unsigned short* __restrict__ W1t_hi, const unsigned short* __restrict__ W1t_lo,
    const float* __restrict__ gamma, const float* __restrict__ beta,
    half_t* __restrict__ t, int nrows, int g1a) {
  __shared__ __align__(16) char smem[36864];
  if ((int)blockIdx.x < NB)
    sort_body(smem, blockIdx.x, binned, bbase, srcs, offs, dinv, N, NB, E);
  else
    gemm_body<256, 128, true>(smem, g1a + (blockIdx.x - NB), x, W1t_hi, W1t_lo,
                              gamma, beta, t, nrows);
}

// ---------------- fused agg + GEMM (layers 2/3), R25 form ------------------
// Phase A: wave-per-node, 4 quarter-waves stride-4 over edges (R7 pattern):
// 16 edges per latency step, degree variance averaged 4-way. Each wave does
// 8 nodes sequentially. shfl_xor(16/32) reduce; qw==0 writes As row.
// Phase B: dual Bs buffers (R21 verified form). <= 64 VGPR (R19/R20 cliff).
template <int NOUT>
__global__ __launch_bounds__(256) void agg_gemm(
    const half_t* __restrict__ tin,
    const int* __restrict__ offs, const int* __restrict__ srcs,
    const float* __restrict__ dinv, const float* __restrict__ bias,
    const unsigned short* __restrict__ Wt_hi,
    const unsigned short* __restrict__ Wt_lo,
    half_t* __restrict__ out, int nrows) {
  constexpr int K = 128, BK = 32, BKP = BK + 8, ROWP = K + 8;
  constexpr int NTW = NOUT / 32;
  __shared__ __align__(16) half_t As[32 * ROWP];        // 8704 B
  __shared__ __align__(16) half_t Bs_hi[NOUT * BKP];
  __shared__ __align__(16) half_t Bs_lo[NOUT * BKP];

  const int tid = threadIdx.x;
  const int row0 = blockIdx.x * 32;
  const int lane = tid & 63;
  const int w = tid >> 6;
  const int quad = lane >> 4;
  const int l16 = lane & 15;

  // ---- phase A: wave-per-node, quarter-wave edge split ----
  {
    const int qw = quad;          // quarter-wave 0..3
    const int fl = l16;           // row segment 0..15
    const half_t* tf = tin + fl * 8;
    float4 b0v = *(const float4*)(bias + fl * 8);
    float4 b1v = *(const float4*)(bias + fl * 8 + 4);
    float bb[8] = {b0v.x, b0v.y, b0v.z, b0v.w, b1v.x, b1v.y, b1v.z, b1v.w};
    for (int rr = 0; rr < 8; ++rr) {
      int node = row0 + w * 8 + rr;
      if (node > nrows - 1) node = nrows - 1;
      int e0 = offs[node], e1 = offs[node + 1];
      float acc[8] = {0.f, 0.f, 0.f, 0.f, 0.f, 0.f, 0.f, 0.f};
      int e = e0 + qw;
      for (; e + 12 < e1; e += 16) {
        int sa = srcs[e], sb = srcs[e + 4], sc = srcs[e + 8], sd = srcs[e + 12];
        float wa = dinv[sa], wb = dinv[sb], wc = dinv[sc], wd = dinv[sd];
        half8_t va = *(const half8_t*)(tf + ((size_t)sa << 7));
        half8_t vb = *(const half8_t*)(tf + ((size_t)sb << 7));
        half8_t vc = *(const half8_t*)(tf + ((size_t)sc << 7));
        half8_t vd = *(const half8_t*)(tf + ((size_t)sd << 7));
#pragma unroll
        for (int j = 0; j < 8; ++j) {
          acc[j] = fmaf(wa, (float)va[j], acc[j]);
          acc[j] = fmaf(wb, (float)vb[j], acc[j]);
          acc[j] = fmaf(wc, (float)vc[j], acc[j]);
          acc[j] = fmaf(wd, (float)vd[j], acc[j]);
        }
      }
      for (; e < e1; e += 4) {
        int s = srcs[e];
        float wv = dinv[s];
        half8_t v = *(const half8_t*)(tf + ((size_t)s << 7));
#pragma unroll
        for (int j = 0; j < 8; ++j) acc[j] = fmaf(wv, (float)v[j], acc[j]);
      }
#pragma unroll
      for (int j = 0; j < 8; ++j) {
        acc[j] += __shfl_xor(acc[j], 16);
        acc[j] += __shfl_xor(acc[j], 32);
      }
      if (qw == 0) {
        float di = dinv[node];
        float dii = di * di;
        half8_t sv = *(const half8_t*)(tf + ((size_t)node << 7));
#pragma unroll
        for (int j = 0; j < 8; ++j) {
          float v = di * acc[j] + dii * (float)sv[j] + bb[j];
          As[(w * 8 + rr) * ROWP + fl * 8 + j] = (half_t)fmaxf(v, 0.f);
        }
      }
    }
  }
  __syncthreads();

  // ---- phase B: f16 dual-MFMA GEMM, A from LDS, W staged in LDS ----
  const int rg = (w & 1) * 16;
  const int cg = (w >> 1) * (NOUT / 2);

  f32x4 acc1[NTW], acc2[NTW];
#pragma unroll
  for (int t = 0; t < NTW; ++t) {
    acc1[t] = (f32x4){0.f, 0.f, 0.f, 0.f};
    acc2[t] = (f32x4){0.f, 0.f, 0.f, 0.f};
  }

  for (int k0 = 0; k0 < K; k0 += BK) {
#pragma unroll
    for (int i = 0; i < NOUT / 64; ++i) {
      int n = i * 64 + (tid >> 2);
      int c8 = (tid & 3) * 8;
      *(uint4*)&Bs_hi[n * BKP + c8] = *(const uint4*)&Wt_hi[(size_t)n * K + k0 + c8];
      *(uint4*)&Bs_lo[n * BKP + c8] = *(const uint4*)&Wt_lo[(size_t)n * K + k0 + c8];
    }
    __syncthreads();

    half8_t av = *(const half8_t*)&As[(rg + l16) * ROWP + k0 + quad * 8];
#pragma unroll
    for (int t = 0; t < NTW; ++t) {
      half8_t bh = *(const half8_t*)&Bs_hi[(cg + t * 16 + l16) * BKP + quad * 8];
      half8_t bl = *(const half8_t*)&Bs_lo[(cg + t * 16 + l16) * BKP + quad * 8];
      acc1[t] = __builtin_amdgcn_mfma_f32_16x16x32_f16(av, bh, acc1[t], 0, 0, 0);
      acc2[t] = __builtin_amdgcn_mfma_f32_16x16x32_f16(av, bl, acc2[t], 0, 0, 0);
    }
    __syncthreads();
  }

#pragma unroll
  for (int t = 0; t < NTW; ++t) {
#pragma unroll
    for (int r = 0; r < 4; ++r) {
      int grow = row0 + rg + quad * 4 + r;
      if (grow < nrows)
        out[(size_t)grow * NOUT + cg + t * 16 + l16] =
            (half_t)(acc1[t][r] + acc2[t][r] * (1.0f / 2048.0f));
    }
  }
}

// ---------------- final aggregation (64-wide, fp32 out) --------------------
__global__ __launch_bounds__(256) void agg64_h(const half_t* __restrict__ t,
                                               const int* __restrict__ offs,
                                               const int* __restrict__ srcs,
                                               const float* __restrict__ dinv,
                                               const float* __restrict__ bias,
                                               float* __restrict__ out, int n) {
  int gid = blockIdx.x * blockDim.x + threadIdx.x;
  int node = gid >> 6, lane = gid & 63;
  if (node >= n) return;
  int og = lane >> 3;
  int fl = lane & 7;
  int e0 = offs[node], e1 = offs[node + 1];
  float acc[8] = {0.f, 0.f, 0.f, 0.f, 0.f, 0.f, 0.f, 0.f};
  int e = e0 + og;
  for (; e + 8 < e1; e += 16) {
    int sa = srcs[e], sb = srcs[e + 8];
    float wa = dinv[sa], wb = dinv[sb];
    half8_t va = *(const half8_t*)(t + ((size_t)sa << 6) + fl * 8);
    half8_t vb = *(const half8_t*)(t + ((size_t)sb << 6) + fl * 8);
#pragma unroll
    for (int j = 0; j < 8; ++j) {
      acc[j] = fmaf(wa, (float)va[j], acc[j]);
      acc[j] = fmaf(wb, (float)vb[j], acc[j]);
    }
  }
  for (; e < e1; e += 8) {
    int s = srcs[e];
    float w = dinv[s];
    half8_t v = *(const half8_t*)(t + ((size_t)s << 6) + fl * 8);
#pragma unroll
    for (int j = 0; j < 8; ++j) acc[j] = fmaf(w, (float)v[j], acc[j]);
  }
#pragma unroll
  for (int j = 0; j < 8; ++j) {
    acc[j] += __shfl_xor(acc[j], 8);
    acc[j] += __shfl_xor(acc[j], 16);
    acc[j] += __shfl_xor(acc[j], 32);
  }
  if (og == 0) {
    float di = dinv[node];
    float dii = di * di;
    half8_t sv = *(const half8_t*)(t + ((size_t)node << 6) + fl * 8);
    float4 b0 = *(const float4*)(bias + fl * 8);
    float4 b1 = *(const float4*)(bias + fl * 8 + 4);
    float bb[8] = {b0.x, b0.y, b0.z, b0.w, b1.x, b1.y, b1.z, b1.w};
    float ov[8];
#pragma unroll
    for (int j = 0; j < 8; ++j) ov[j] = di * acc[j] + dii * (float)sv[j] + bb[j];
    *(float4*)(out + ((size_t)node << 6) + fl * 8) = make_float4(ov[0], ov[1], ov[2], ov[3]);
    *(float4*)(out + ((size_t)node << 6) + fl * 8 + 4) = make_float4(ov[4], ov[5], ov[6], ov[7]);
  }
}

extern "C" void kernel_launch(void* const* d_in, const int* in_sizes, int n_in,
                              void* d_out, int out_size, void* d_ws, size_t ws_size,
                              hipStream_t stream) {
  const float* x = (const float*)d_in[0];
  const int* ei = (const int*)d_in[1];
  const float* gamma = (const float*)d_in[2];
  const float* beta = (const float*)d_in[3];
  const float* W1 = (const float*)d_in[4];
  const float* b1 = (const float*)d_in[5];
  const float* W2 = (const float*)d_in[6];
  const float* b2 = (const float*)d_in[7];
  const float* W3 = (const float*)d_in[8];
  const float* b3 = (const float*)d_in[9];
  float* out = (float*)d_out;

  const int N = in_sizes[0] / 256;  // 50000 < 65536: packed records valid
  const int E = in_sizes[1] / 2;
  const int* src = ei;
  const int* dst = ei + E;
  const int NB = (N + 255) >> 8;

  char* ws = (char*)d_ws;
  auto alloc = [&](size_t bytes) -> char* {
    char* p = ws;
    ws += (bytes + 255) & ~(size_t)255;
    return p;
  };
  int* bcnt_multi = (int*)alloc(NHIST * 256 * 4);
  int* bbase = (int*)alloc(257 * 4);
  int* bcur = (int*)alloc(256 * 4);
  unsigned int* binned = (unsigned int*)alloc((size_t)E * 4);
  int* srcs = (int*)alloc((size_t)E * 4);
  int* offs = (int*)alloc((size_t)(N + 1) * 4);
  float* dinv = (float*)alloc((size_t)N * 4);
  half_t* t = (half_t*)alloc((size_t)N * 128 * 2);
  half_t* h = (half_t*)alloc((size_t)N * 128 * 2);
  unsigned short* W1t_hi = (unsigned short*)alloc(256 * 128 * 2);
  unsigned short* W1t_lo = (unsigned short*)alloc(256 * 128 * 2);
  unsigned short* W2t_hi = (unsigned short*)alloc(128 * 128 * 2);
  unsigned short* W2t_lo = (unsigned short*)alloc(128 * 128 * 2);
  unsigned short* W3t_hi = (unsigned short*)alloc(128 * 64 * 2);
  unsigned short* W3t_lo = (unsigned short*)alloc(128 * 64 * 2);

  // ---- prep: hist x256 + wsplit x3 in one launch ----
  prep_misc<<<NHIST + 224, 256, 0, stream>>>(
      dst, W1, W2, W3, bcnt_multi, W1t_hi, W1t_lo, W2t_hi, W2t_lo,
      W3t_hi, W3t_lo, E);

  // ---- scan ----
  scan_buckets<<<1, 256, 0, stream>>>(bcnt_multi, bbase, bcur, NB, E);

  const int gemm_blocks = (N + 31) / 32;  // BM=32
  const int G1A = gemm_blocks / 2;
  const int G1B = gemm_blocks - G1A;
  const int NSCAT = (E + CHUNK - 1) / CHUNK;
  const int agg_blocks = (N + 3) / 4;

  // ---- CSR scatter ∥ GEMM1 (first half) ----
  fused_scatter_gemm1<<<NSCAT + G1A, 256, 0, stream>>>(
      src, dst, bcur, binned, E, x, W1t_hi, W1t_lo, gamma, beta, t, N, NSCAT);

  // ---- CSR sort ∥ GEMM1 (second half) ----
  fused_sort_gemm1<<<NB + G1B, 256, 0, stream>>>(
      binned, bbase, srcs, offs, dinv, N, NB, E, x, W1t_hi, W1t_lo, gamma, beta,
      t, N, G1A);

  // ---- layer 2: agg(t)+relu+b1 then @W2 -> h ----
  agg_gemm<128><<<gemm_blocks, 256, 0, stream>>>(
      t, offs, srcs, dinv, b1, W2t_hi, W2t_lo, h, N);

  // ---- layer 3: agg(h)+relu+b2 then @W3 -> t ----
  agg_gemm<64><<<gemm_blocks, 256, 0, stream>>>(
      h, offs, srcs, dinv, b2, W3t_hi, W3t_lo, t, N);

  // ---- final aggregation ----
  agg64_h<<<agg_blocks, 256, 0, stream>>>(t, offs, srcs, dinv, b3, out, N);
}

// Round 15
// 258.662 us; speedup vs baseline: 1.1262x; 1.1262x over previous
//
#include <hip/hip_runtime.h>
#include <cstdint>
#include <cstddef>

// ---------------------------------------------------------------------------
// GCN encoder: z = GCN3( relu(GCN2( relu(GCN1( LN(x) )) )) )
// R26: clean revert to R21 (verified 259.5us), the best reproducible state.
//      Gather post-mortem across R19/R20/R23/R24/R25: all five phase-A
//      restructures regressed or were flat. Model: the three aggregations
//      gather ~512MB of random 256B rows at a measured ~4.5TB/s pattern
//      floor (~115us irreducible); gather widths already minimal
//      (128/128/64-wide at each stage); rows read as single coalesced 256B
//      requests; random graph -> no locality to tile. CONSTRAINTS:
//      agg_gemm <= 64 VGPR (R19/R20 cliff); row-per-16-lane-group phase A
//      (R25: wave-per-node reduce overhead regresses); W staged via LDS
//      (R19: direct-global W creates device-wide L2 hotspot).
// ---------------------------------------------------------------------------

typedef __attribute__((ext_vector_type(8))) __bf16 bf16x8;
typedef __attribute__((ext_vector_type(4))) float f32x4;
typedef _Float16 half_t;
typedef __attribute__((ext_vector_type(8))) _Float16 half8_t;

#define NHIST 256
#define CHUNK 4096
#define MAXB 8192

// ---------------- prep: hist x256 | wsplit x3, by block range --------------
__global__ __launch_bounds__(256) void prep_misc(
    const int* __restrict__ dst,
    const float* __restrict__ W1, const float* __restrict__ W2,
    const float* __restrict__ W3,
    int* __restrict__ bcnt_multi,
    unsigned short* __restrict__ W1t_hi, unsigned short* __restrict__ W1t_lo,
    unsigned short* __restrict__ W2t_hi, unsigned short* __restrict__ W2t_lo,
    unsigned short* __restrict__ W3t_hi, unsigned short* __restrict__ W3t_lo,
    int E) {
  int blk = blockIdx.x;
  int tid = threadIdx.x;
  if (blk < NHIST) {
    __shared__ int h[256];
    h[tid] = 0;
    __syncthreads();
    for (int e = blk * 256 + tid; e < E; e += NHIST * 256)
      atomicAdd(&h[dst[e] >> 8], 1);
    __syncthreads();
    bcnt_multi[blk * 256 + tid] = h[tid];
    return;
  }
  int idx = (blk - NHIST) * 256 + tid;
  if (idx < 32768) {
    // W1: bf16 hi/lo (layer-1 bf16-triple path)
    int k = idx / 128, c = idx % 128;
    float v = W1[idx];
    __bf16 h = (__bf16)v;
    __bf16 l = (__bf16)(v - (float)h);
    W1t_hi[(size_t)c * 256 + k] = __builtin_bit_cast(unsigned short, h);
    W1t_lo[(size_t)c * 256 + k] = __builtin_bit_cast(unsigned short, l);
    return;
  }
  // W2/W3: fp16 hi + fp16 lo*2048 (f16 dual-MFMA path)
  const float* W;
  unsigned short *Th, *Tl;
  int K, NOUT;
  if (idx < 49152) {
    idx -= 32768;
    W = W2; Th = W2t_hi; Tl = W2t_lo; K = 128; NOUT = 128;
  } else {
    idx -= 49152;
    W = W3; Th = W3t_hi; Tl = W3t_lo; K = 128; NOUT = 64;
  }
  int k = idx / NOUT, c = idx % NOUT;
  float v = W[idx];
  half_t h = (half_t)v;
  half_t l = (half_t)((v - (float)h) * 2048.0f);
  Th[(size_t)c * K + k] = __builtin_bit_cast(unsigned short, h);
  Tl[(size_t)c * K + k] = __builtin_bit_cast(unsigned short, l);
}

// ---------------- scan: sum 256 slices, exclusive prefix ----------------
__global__ __launch_bounds__(256) void scan_buckets(const int* __restrict__ bcnt_multi,
                                                    int* __restrict__ bbase,
                                                    int* __restrict__ bcur, int NB, int E) {
  __shared__ int tmp[256];
  int t = threadIdx.x;
  int v = 0;
  for (int h = 0; h < NHIST; ++h) v += bcnt_multi[h * 256 + t];
  tmp[t] = v;
  __syncthreads();
  for (int off = 1; off < 256; off <<= 1) {
    int x = (t >= off) ? tmp[t - off] : 0;
    __syncthreads();
    tmp[t] += x;
    __syncthreads();
  }
  int excl = tmp[t] - v;
  if (t < NB) { bbase[t] = excl; bcur[t] = excl; }
  if (t == 0) bbase[NB] = E;
}

// ---------------- scatter body (smem: 20480 B) ----------------
// record = (dst << 16) | src  (both < 65536)
__device__ __forceinline__ void scatter_body(char* smem_raw, int bid,
                                             const int* __restrict__ src,
                                             const int* __restrict__ dst,
                                             int* __restrict__ bcur,
                                             unsigned int* __restrict__ binned, int E) {
  unsigned int* recs = (unsigned int*)smem_raw;          // 16384 B
  int* hist = (int*)(smem_raw + 16384);
  int* lbase = hist + 256;
  int* resv = lbase + 256;
  int* cur = resv + 256;
  int t = threadIdx.x;
  int e0 = bid * CHUNK;
  if (e0 >= E) return;
  int len = min(CHUNK, E - e0);
  hist[t] = 0;
  cur[t] = 0;
  __syncthreads();
  for (int i = t; i < len; i += 256) atomicAdd(&hist[dst[e0 + i] >> 8], 1);
  __syncthreads();
  int v = hist[t];
  lbase[t] = v;
  __syncthreads();
  for (int off = 1; off < 256; off <<= 1) {
    int x = (t >= off) ? lbase[t - off] : 0;
    __syncthreads();
    lbase[t] += x;
    __syncthreads();
  }
  int myexcl = lbase[t] - v;
  if (v) resv[t] = atomicAdd(&bcur[t], v);
  __syncthreads();
  lbase[t] = myexcl;
  __syncthreads();
  for (int i = t; i < len; i += 256) {
    int d = dst[e0 + i], s = src[e0 + i];
    int b = d >> 8;
    int r = atomicAdd(&cur[b], 1);
    recs[lbase[b] + r] = ((unsigned int)d << 16) | (unsigned int)s;
  }
  __syncthreads();
  for (int i = t; i < len; i += 256) {
    unsigned int rc = recs[i];
    int b = rc >> 24;
    binned[resv[b] + (i - lbase[b])] = rc;
  }
}

// ---------------- sort body (smem: 36864 B) ----------------
__device__ __forceinline__ void sort_body(char* smem_raw, int b,
                                          const unsigned int* __restrict__ binned,
                                          const int* __restrict__ bbase,
                                          int* __restrict__ srcs,
                                          int* __restrict__ offs,
                                          float* __restrict__ dinv,
                                          int N, int NB, int E) {
  int* sstage = (int*)smem_raw;                           // 32768 B
  int* hist = (int*)(smem_raw + 32768);
  int* nbase = hist + 256;
  int* cur = nbase + 256;
  int* tmp = cur + 256;
  int t = threadIdx.x;
  int base = bbase[b], end = bbase[b + 1];
  int L = end - base;
  if (L > MAXB) L = MAXB;
  hist[t] = 0;
  __syncthreads();
  for (int i = t; i < L; i += 256)
    atomicAdd(&hist[(binned[base + i] >> 16) & 255], 1);
  __syncthreads();
  int v = hist[t];
  tmp[t] = v;
  __syncthreads();
  for (int off = 1; off < 256; off <<= 1) {
    int x = (t >= off) ? tmp[t - off] : 0;
    __syncthreads();
    tmp[t] += x;
    __syncthreads();
  }
  int excl = tmp[t] - v;
  nbase[t] = excl;
  cur[t] = excl;
  int node = (b << 8) + t;
  if (node < N) {
    offs[node] = base + excl;
    dinv[node] = rsqrtf(1.0f + (float)v);
  }
  if (b == NB - 1 && t == 0) offs[N] = E;
  __syncthreads();
  for (int i = t; i < L; i += 256) {
    unsigned int p = binned[base + i];
    int ld = (p >> 16) & 255;
    int slot = atomicAdd(&cur[ld], 1);
    sstage[slot] = (int)(p & 0xFFFFu);
  }
  __syncthreads();
  for (int i = t; i < L; i += 256) srcs[base + i] = sstage[i];
}

// ---------------- GEMM1 body: BM=32, bf16 hi/lo triple-MFMA, LN fused ------
template <int K, int NOUT, bool LN>
__device__ __forceinline__ void gemm_body(char* smem_raw, int gbid,
                                          const float* __restrict__ A,
                                          const unsigned short* __restrict__ Wt_hi,
                                          const unsigned short* __restrict__ Wt_lo,
                                          const float* __restrict__ gamma,
                                          const float* __restrict__ beta,
                                          half_t* __restrict__ out, int nrows) {
  constexpr int BM = 32, BK = 32, BKP = BK + 8;
  constexpr int NTW = NOUT / 32;

  const int tid = threadIdx.x;
  const int lane = tid & 63;
  const int w = tid >> 6;
  const int quad = lane >> 4;
  const int l16 = lane & 15;
  const int rg = (w & 1) * 16;
  const int cg = (w >> 1) * (NOUT / 2);
  const int row0 = gbid * BM;

  unsigned short* As_hi = (unsigned short*)smem_raw;
  unsigned short* As_lo = As_hi + BM * BKP;
  unsigned short* Bs_hi = As_lo + BM * BKP;
  unsigned short* Bs_lo = Bs_hi + NOUT * BKP;
  float* mu_s = (float*)(Bs_lo + NOUT * BKP);
  float* rs_s = mu_s + BM;

  if constexpr (LN) {
    int r = tid >> 3;
    int part = tid & 7;
    int grow = row0 + r;
    if (grow > nrows - 1) grow = nrows - 1;
    const float4* rp = (const float4*)(A + (size_t)grow * K);
    float s = 0.f, s2 = 0.f;
#pragma unroll
    for (int j = 0; j < K / 32; ++j) {
      float4 v = rp[part * (K / 32) + j];
      s += v.x + v.y + v.z + v.w;
      s2 += v.x * v.x + v.y * v.y + v.z * v.z + v.w * v.w;
    }
    s += __shfl_xor(s, 1);
    s += __shfl_xor(s, 2);
    s += __shfl_xor(s, 4);
    s2 += __shfl_xor(s2, 1);
    s2 += __shfl_xor(s2, 2);
    s2 += __shfl_xor(s2, 4);
    if (part == 0) {
      float m = s * (1.0f / (float)K);
      float var = s2 * (1.0f / (float)K) - m * m;
      mu_s[r] = m;
      rs_s[r] = rsqrtf(var + 1e-5f);
    }
    __syncthreads();
  }

  f32x4 acc[NTW];
#pragma unroll
  for (int t = 0; t < NTW; ++t) acc[t] = (f32x4){0.f, 0.f, 0.f, 0.f};

  for (int k0 = 0; k0 < K; k0 += BK) {
    {
      int r = tid >> 3;
      int c4 = (tid & 7) * 4;
      int grow = row0 + r;
      if (grow > nrows - 1) grow = nrows - 1;
      float4 v = *(const float4*)&A[(size_t)grow * K + k0 + c4];
      if constexpr (LN) {
        float m = mu_s[r], s = rs_s[r];
        float4 g = *(const float4*)&gamma[k0 + c4];
        float4 b = *(const float4*)&beta[k0 + c4];
        v.x = (v.x - m) * s * g.x + b.x;
        v.y = (v.y - m) * s * g.y + b.y;
        v.z = (v.z - m) * s * g.z + b.z;
        v.w = (v.w - m) * s * g.w + b.w;
      }
      float vv[4] = {v.x, v.y, v.z, v.w};
#pragma unroll
      for (int j = 0; j < 4; ++j) {
        __bf16 h = (__bf16)vv[j];
        __bf16 l = (__bf16)(vv[j] - (float)h);
        As_hi[r * BKP + c4 + j] = __builtin_bit_cast(unsigned short, h);
        As_lo[r * BKP + c4 + j] = __builtin_bit_cast(unsigned short, l);
      }
    }
#pragma unroll
    for (int i = 0; i < NOUT / 64; ++i) {
      int n = i * 64 + (tid >> 2);
      int c8 = (tid & 3) * 8;
      *(uint4*)&Bs_hi[n * BKP + c8] = *(const uint4*)&Wt_hi[(size_t)n * K + k0 + c8];
      *(uint4*)&Bs_lo[n * BKP + c8] = *(const uint4*)&Wt_lo[(size_t)n * K + k0 + c8];
    }
    __syncthreads();

    bf16x8 ah = *(const bf16x8*)&As_hi[(rg + l16) * BKP + quad * 8];
    bf16x8 al = *(const bf16x8*)&As_lo[(rg + l16) * BKP + quad * 8];
#pragma unroll
    for (int t = 0; t < NTW; ++t) {
      bf16x8 bh = *(const bf16x8*)&Bs_hi[(cg + t * 16 + l16) * BKP + quad * 8];
      bf16x8 bl = *(const bf16x8*)&Bs_lo[(cg + t * 16 + l16) * BKP + quad * 8];
      acc[t] = __builtin_amdgcn_mfma_f32_16x16x32_bf16(ah, bh, acc[t], 0, 0, 0);
      acc[t] = __builtin_amdgcn_mfma_f32_16x16x32_bf16(al, bh, acc[t], 0, 0, 0);
      acc[t] = __builtin_amdgcn_mfma_f32_16x16x32_bf16(ah, bl, acc[t], 0, 0, 0);
    }
    __syncthreads();
  }

#pragma unroll
  for (int t = 0; t < NTW; ++t) {
#pragma unroll
    for (int r = 0; r < 4; ++r) {
      int grow = row0 + rg + quad * 4 + r;
      if (grow < nrows)
        out[(size_t)grow * NOUT + cg + t * 16 + l16] = (half_t)acc[t][r];
    }
  }
}

constexpr int GEMM1_SMEM = 32 * 40 * 4 + 128 * 40 * 4 + 256;  // 25856

__global__ __launch_bounds__(256) void fused_scatter_gemm1(
    const int* __restrict__ src, const int* __restrict__ dst,
    int* __restrict__ bcur, unsigned int* __restrict__ binned, int E,
    const float* __restrict__ x,
    const unsigned short* __restrict__ W1t_hi, const unsigned short* __restrict__ W1t_lo,
    const float* __restrict__ gamma, const float* __restrict__ beta,
    half_t* __restrict__ t, int nrows, int nscat) {
  __shared__ __align__(16) char smem[GEMM1_SMEM];
  if ((int)blockIdx.x < nscat)
    scatter_body(smem, blockIdx.x, src, dst, bcur, binned, E);
  else
    gemm_body<256, 128, true>(smem, blockIdx.x - nscat, x, W1t_hi, W1t_lo,
                              gamma, beta, t, nrows);
}

__global__ __launch_bounds__(256) void fused_sort_gemm1(
    const unsigned int* __restrict__ binned, const int* __restrict__ bbase,
    int* __restrict__ srcs, int* __restrict__ offs, float* __restrict__ dinv,
    int N, int NB, int E,
    const float* __restrict__ x,
    const unsigned short* __restrict__ W1t_hi, const unsigned short* __restrict__ W1t_lo,
    const float* __restrict__ gamma, const float* __restrict__ beta,
    half_t* __restrict__ t, int nrows, int g1a) {
  __shared__ __align__(16) char smem[36864];
  if ((int)blockIdx.x < NB)
    sort_body(smem, blockIdx.x, binned, bbase, srcs, offs, dinv, N, NB, E);
  else
    gemm_body<256, 128, true>(smem, g1a + (blockIdx.x - NB), x, W1t_hi, W1t_lo,
                              gamma, beta, t, nrows);
}

// ---------------- fused agg + GEMM (layers 2/3), R18/R21 form --------------
// Phase A: one row per 16-lane group, 4-edge batches (<= 64 VGPR; R19/R20
// cliff). Phase B: dual Bs LDS staging (R19: direct-global W = L2 hotspot).
template <int NOUT>
__global__ __launch_bounds__(256) void agg_gemm(
    const half_t* __restrict__ tin,
    const int* __restrict__ offs, const int* __restrict__ srcs,
    const float* __restrict__ dinv, const float* __restrict__ bias,
    const unsigned short* __restrict__ Wt_hi,
    const unsigned short* __restrict__ Wt_lo,
    half_t* __restrict__ out, int nrows) {
  constexpr int K = 128, BK = 32, BKP = BK + 8, ROWP = K + 8;
  constexpr int NTW = NOUT / 32;
  __shared__ __align__(16) half_t As[32 * ROWP];        // 8704 B
  __shared__ __align__(16) half_t Bs_hi[NOUT * BKP];
  __shared__ __align__(16) half_t Bs_lo[NOUT * BKP];

  const int tid = threadIdx.x;
  const int row0 = blockIdx.x * 32;

  // ---- phase A: aggregate 32 rows into As (one row per 16-lane group) ----
  {
    int g = tid >> 4, fl = tid & 15;
#pragma unroll
    for (int rr = g; rr < 32; rr += 16) {
      int node = row0 + rr;
      if (node > nrows - 1) node = nrows - 1;
      int e0 = offs[node], e1 = offs[node + 1];
      float acc[8] = {0.f, 0.f, 0.f, 0.f, 0.f, 0.f, 0.f, 0.f};
      int e = e0;
      for (; e + 3 < e1; e += 4) {
        int sa = srcs[e], sb = srcs[e + 1], sc = srcs[e + 2], sd = srcs[e + 3];
        float wa = dinv[sa], wb = dinv[sb], wc = dinv[sc], wd = dinv[sd];
        half8_t va = *(const half8_t*)(tin + ((size_t)sa << 7) + fl * 8);
        half8_t vb = *(const half8_t*)(tin + ((size_t)sb << 7) + fl * 8);
        half8_t vc = *(const half8_t*)(tin + ((size_t)sc << 7) + fl * 8);
        half8_t vd = *(const half8_t*)(tin + ((size_t)sd << 7) + fl * 8);
#pragma unroll
        for (int j = 0; j < 8; ++j) {
          acc[j] = fmaf(wa, (float)va[j], acc[j]);
          acc[j] = fmaf(wb, (float)vb[j], acc[j]);
          acc[j] = fmaf(wc, (float)vc[j], acc[j]);
          acc[j] = fmaf(wd, (float)vd[j], acc[j]);
        }
      }
      for (; e < e1; ++e) {
        int s = srcs[e];
        float w = dinv[s];
        half8_t v = *(const half8_t*)(tin + ((size_t)s << 7) + fl * 8);
#pragma unroll
        for (int j = 0; j < 8; ++j) acc[j] = fmaf(w, (float)v[j], acc[j]);
      }
      float di = dinv[node];
      float dii = di * di;
      half8_t sv = *(const half8_t*)(tin + ((size_t)node << 7) + fl * 8);
      float4 b0 = *(const float4*)(bias + fl * 8);
      float4 b1 = *(const float4*)(bias + fl * 8 + 4);
      float bb[8] = {b0.x, b0.y, b0.z, b0.w, b1.x, b1.y, b1.z, b1.w};
#pragma unroll
      for (int j = 0; j < 8; ++j) {
        float v = di * acc[j] + dii * (float)sv[j] + bb[j];
        As[rr * ROWP + fl * 8 + j] = (half_t)fmaxf(v, 0.f);
      }
    }
  }
  __syncthreads();

  // ---- phase B: f16 dual-MFMA GEMM, A from LDS, W staged in LDS ----
  const int lane = tid & 63;
  const int w = tid >> 6;
  const int quad = lane >> 4;
  const int l16 = lane & 15;
  const int rg = (w & 1) * 16;
  const int cg = (w >> 1) * (NOUT / 2);

  f32x4 acc1[NTW], acc2[NTW];
#pragma unroll
  for (int t = 0; t < NTW; ++t) {
    acc1[t] = (f32x4){0.f, 0.f, 0.f, 0.f};
    acc2[t] = (f32x4){0.f, 0.f, 0.f, 0.f};
  }

  for (int k0 = 0; k0 < K; k0 += BK) {
#pragma unroll
    for (int i = 0; i < NOUT / 64; ++i) {
      int n = i * 64 + (tid >> 2);
      int c8 = (tid & 3) * 8;
      *(uint4*)&Bs_hi[n * BKP + c8] = *(const uint4*)&Wt_hi[(size_t)n * K + k0 + c8];
      *(uint4*)&Bs_lo[n * BKP + c8] = *(const uint4*)&Wt_lo[(size_t)n * K + k0 + c8];
    }
    __syncthreads();

    half8_t av = *(const half8_t*)&As[(rg + l16) * ROWP + k0 + quad * 8];
#pragma unroll
    for (int t = 0; t < NTW; ++t) {
      half8_t bh = *(const half8_t*)&Bs_hi[(cg + t * 16 + l16) * BKP + quad * 8];
      half8_t bl = *(const half8_t*)&Bs_lo[(cg + t * 16 + l16) * BKP + quad * 8];
      acc1[t] = __builtin_amdgcn_mfma_f32_16x16x32_f16(av, bh, acc1[t], 0, 0, 0);
      acc2[t] = __builtin_amdgcn_mfma_f32_16x16x32_f16(av, bl, acc2[t], 0, 0, 0);
    }
    __syncthreads();
  }

#pragma unroll
  for (int t = 0; t < NTW; ++t) {
#pragma unroll
    for (int r = 0; r < 4; ++r) {
      int grow = row0 + rg + quad * 4 + r;
      if (grow < nrows)
        out[(size_t)grow * NOUT + cg + t * 16 + l16] =
            (half_t)(acc1[t][r] + acc2[t][r] * (1.0f / 2048.0f));
    }
  }
}

// ---------------- final aggregation (64-wide, fp32 out) --------------------
__global__ __launch_bounds__(256) void agg64_h(const half_t* __restrict__ t,
                                               const int* __restrict__ offs,
                                               const int* __restrict__ srcs,
                                               const float* __restrict__ dinv,
                                               const float* __restrict__ bias,
                                               float* __restrict__ out, int n) {
  int gid = blockIdx.x * blockDim.x + threadIdx.x;
  int node = gid >> 6, lane = gid & 63;
  if (node >= n) return;
  int og = lane >> 3;
  int fl = lane & 7;
  int e0 = offs[node], e1 = offs[node + 1];
  float acc[8] = {0.f, 0.f, 0.f, 0.f, 0.f, 0.f, 0.f, 0.f};
  int e = e0 + og;
  for (; e + 8 < e1; e += 16) {
    int sa = srcs[e], sb = srcs[e + 8];
    float wa = dinv[sa], wb = dinv[sb];
    half8_t va = *(const half8_t*)(t + ((size_t)sa << 6) + fl * 8);
    half8_t vb = *(const half8_t*)(t + ((size_t)sb << 6) + fl * 8);
#pragma unroll
    for (int j = 0; j < 8; ++j) {
      acc[j] = fmaf(wa, (float)va[j], acc[j]);
      acc[j] = fmaf(wb, (float)vb[j], acc[j]);
    }
  }
  for (; e < e1; e += 8) {
    int s = srcs[e];
    float w = dinv[s];
    half8_t v = *(const half8_t*)(t + ((size_t)s << 6) + fl * 8);
#pragma unroll
    for (int j = 0; j < 8; ++j) acc[j] = fmaf(w, (float)v[j], acc[j]);
  }
#pragma unroll
  for (int j = 0; j < 8; ++j) {
    acc[j] += __shfl_xor(acc[j], 8);
    acc[j] += __shfl_xor(acc[j], 16);
    acc[j] += __shfl_xor(acc[j], 32);
  }
  if (og == 0) {
    float di = dinv[node];
    float dii = di * di;
    half8_t sv = *(const half8_t*)(t + ((size_t)node << 6) + fl * 8);
    float4 b0 = *(const float4*)(bias + fl * 8);
    float4 b1 = *(const float4*)(bias + fl * 8 + 4);
    float bb[8] = {b0.x, b0.y, b0.z, b0.w, b1.x, b1.y, b1.z, b1.w};
    float ov[8];
#pragma unroll
    for (int j = 0; j < 8; ++j) ov[j] = di * acc[j] + dii * (float)sv[j] + bb[j];
    *(float4*)(out + ((size_t)node << 6) + fl * 8) = make_float4(ov[0], ov[1], ov[2], ov[3]);
    *(float4*)(out + ((size_t)node << 6) + fl * 8 + 4) = make_float4(ov[4], ov[5], ov[6], ov[7]);
  }
}

extern "C" void kernel_launch(void* const* d_in, const int* in_sizes, int n_in,
                              void* d_out, int out_size, void* d_ws, size_t ws_size,
                              hipStream_t stream) {
  const float* x = (const float*)d_in[0];
  const int* ei = (const int*)d_in[1];
  const float* gamma = (const float*)d_in[2];
  const float* beta = (const float*)d_in[3];
  const float* W1 = (const float*)d_in[4];
  const float* b1 = (const float*)d_in[5];
  const float* W2 = (const float*)d_in[6];
  const float* b2 = (const float*)d_in[7];
  const float* W3 = (const float*)d_in[8];
  const float* b3 = (const float*)d_in[9];
  float* out = (float*)d_out;

  const int N = in_sizes[0] / 256;  // 50000 < 65536: packed records valid
  const int E = in_sizes[1] / 2;
  const int* src = ei;
  const int* dst = ei + E;
  const int NB = (N + 255) >> 8;

  char* ws = (char*)d_ws;
  auto alloc = [&](size_t bytes) -> char* {
    char* p = ws;
    ws += (bytes + 255) & ~(size_t)255;
    return p;
  };
  int* bcnt_multi = (int*)alloc(NHIST * 256 * 4);
  int* bbase = (int*)alloc(257 * 4);
  int* bcur = (int*)alloc(256 * 4);
  unsigned int* binned = (unsigned int*)alloc((size_t)E * 4);
  int* srcs = (int*)alloc((size_t)E * 4);
  int* offs = (int*)alloc((size_t)(N + 1) * 4);
  float* dinv = (float*)alloc((size_t)N * 4);
  half_t* t = (half_t*)alloc((size_t)N * 128 * 2);
  half_t* h = (half_t*)alloc((size_t)N * 128 * 2);
  unsigned short* W1t_hi = (unsigned short*)alloc(256 * 128 * 2);
  unsigned short* W1t_lo = (unsigned short*)alloc(256 * 128 * 2);
  unsigned short* W2t_hi = (unsigned short*)alloc(128 * 128 * 2);
  unsigned short* W2t_lo = (unsigned short*)alloc(128 * 128 * 2);
  unsigned short* W3t_hi = (unsigned short*)alloc(128 * 64 * 2);
  unsigned short* W3t_lo = (unsigned short*)alloc(128 * 64 * 2);

  // ---- prep: hist x256 + wsplit x3 in one launch ----
  prep_misc<<<NHIST + 224, 256, 0, stream>>>(
      dst, W1, W2, W3, bcnt_multi, W1t_hi, W1t_lo, W2t_hi, W2t_lo,
      W3t_hi, W3t_lo, E);

  // ---- scan ----
  scan_buckets<<<1, 256, 0, stream>>>(bcnt_multi, bbase, bcur, NB, E);

  const int gemm_blocks = (N + 31) / 32;  // BM=32
  const int G1A = gemm_blocks / 2;
  const int G1B = gemm_blocks - G1A;
  const int NSCAT = (E + CHUNK - 1) / CHUNK;
  const int agg_blocks = (N + 3) / 4;

  // ---- CSR scatter ∥ GEMM1 (first half) ----
  fused_scatter_gemm1<<<NSCAT + G1A, 256, 0, stream>>>(
      src, dst, bcur, binned, E, x, W1t_hi, W1t_lo, gamma, beta, t, N, NSCAT);

  // ---- CSR sort ∥ GEMM1 (second half) ----
  fused_sort_gemm1<<<NB + G1B, 256, 0, stream>>>(
      binned, bbase, srcs, offs, dinv, N, NB, E, x, W1t_hi, W1t_lo, gamma, beta,
      t, N, G1A);

  // ---- layer 2: agg(t)+relu+b1 then @W2 -> h ----
  agg_gemm<128><<<gemm_blocks, 256, 0, stream>>>(
      t, offs, srcs, dinv, b1, W2t_hi, W2t_lo, h, N);

  // ---- layer 3: agg(h)+relu+b2 then @W3 -> t ----
  agg_gemm<64><<<gemm_blocks, 256, 0, stream>>>(
      h, offs, srcs, dinv, b2, W3t_hi, W3t_lo, t, N);

  // ---- final aggregation ----
  agg64_h<<<agg_blocks, 256, 0, stream>>>(t, offs, srcs, dinv, b3, out, N);
}